// Round 3
// baseline (7060.001 us; speedup 1.0000x reference)
//
#include <hip/hip_runtime.h>
#include <stdint.h>

#define BN_TOTAL 51200
#define NSEQ 800
#define TIN 15
#define FIN 8
#define TOUT 12
#define HH 64
#define NC 9
#define BT 128

__device__ __forceinline__ float sigm(float x){ return __builtin_amdgcn_rcpf(1.f+__expf(-x)); }
__device__ __forceinline__ float tanhx(float x){ float e=__expf(2.f*x); return 1.f - 2.f*__builtin_amdgcn_rcpf(e+1.f); }

__global__ __launch_bounds__(BT) void gru_kernel(
  const float* __restrict__ X,
  const float* __restrict__ cw2, const float* __restrict__ cw3, const float* __restrict__ cw4,
  const float* __restrict__ cbv,
  const float* __restrict__ Ewih, const float* __restrict__ Ewhh,
  const float* __restrict__ Ebih, const float* __restrict__ Ebhh,
  const float* __restrict__ Dwih, const float* __restrict__ Dwhh,
  const float* __restrict__ Dbih, const float* __restrict__ Dbhh,
  const float* __restrict__ Lw,   const float* __restrict__ Lb,
  const float* __restrict__ emb,
  float* __restrict__ out)
{
  __shared__ float hl[HH*BT];   // h mirror for dynamic-j access; lanes consecutive -> conflict-free
  const int tid = threadIdx.x;
  const int s = blockIdx.x*BT + tid;
  const int r = blockIdx.y;
  const int Kc[NC]={2,2,2,3,3,3,4,4,4};
  const int Dc[NC]={1,2,4,1,2,4,1,2,4};
  const int K = Kc[r], D = Dc[r];
  const int L = TIN - (K-1)*D;

  // conv weight slice: conv_ws = [cw2[0..2], cw3[0..2], cw4[0..2]], each (8,8,K)
  const float* __restrict__ cw = (r<3) ? (cw2 + r*128) : (r<6) ? (cw3 + (r-3)*192) : (cw4 + (r-6)*256);
  const float* __restrict__ cb   = cbv  + r*FIN;
  const float* __restrict__ ewih = Ewih + r*192*FIN;
  const float* __restrict__ ewhh = Ewhh + r*192*HH;
  const float* __restrict__ ebih = Ebih + r*192;
  const float* __restrict__ ebhh = Ebhh + r*192;
  const float* __restrict__ dwih = Dwih + r*192;
  const float* __restrict__ dwhh = Dwhh + r*192*HH;
  const float* __restrict__ dbih = Dbih + r*192;
  const float* __restrict__ dbhh = Dbhh + r*192;
  const float* __restrict__ lw   = Lw   + r*HH;
  const float  lb = Lb[r];
  const float* __restrict__ Xs = X + s*(TIN*FIN);

  // softmax(embed[n])[r]  -- per-sequence channel weight
  const int n = s % NSEQ;
  float e[NC];
  float m = -1e30f;
  #pragma unroll
  for (int c=0;c<NC;c++){ e[c] = emb[n*NC+c]; m = fmaxf(m, e[c]); }
  float esum = 0.f;
  #pragma unroll
  for (int c=0;c<NC;c++){ esum += __expf(e[c]-m); }
  const float wgt = __expf(e[r]-m) / esum;

  float h[HH];
  #pragma unroll
  for (int k=0;k<HH;k++){ h[k]=0.f; hl[k*BT+tid]=0.f; }

  // ---------------- encoder ----------------
  for (int t=0;t<L;t++){
    float xv[4*FIN];
    #pragma unroll
    for (int k=0;k<4;k++) if (k<K){
      const float4 q0 = *(const float4*)(Xs + (t+k*D)*FIN);
      const float4 q1 = *(const float4*)(Xs + (t+k*D)*FIN + 4);
      xv[k*8+0]=q0.x; xv[k*8+1]=q0.y; xv[k*8+2]=q0.z; xv[k*8+3]=q0.w;
      xv[k*8+4]=q1.x; xv[k*8+5]=q1.y; xv[k*8+6]=q1.z; xv[k*8+7]=q1.w;
    }
    float x[FIN];
    #pragma unroll
    for (int o=0;o<FIN;o++){
      float a = cb[o];
      #pragma unroll
      for (int k=0;k<4;k++) if (k<K){
        #pragma unroll
        for (int i=0;i<FIN;i++) a += xv[k*8+i]*cw[(o*8+i)*K + k];
      }
      x[o]=a;
    }

    #pragma unroll 1
    for (int j=0;j<HH;j++){
      float aR = ebih[j]      + ebhh[j];
      float aZ = ebih[64+j]   + ebhh[64+j];
      float aNi= ebih[128+j];
      float aNh= ebhh[128+j];
      const float* wiR = ewih + j*FIN;
      const float* wiZ = ewih + (64+j)*FIN;
      const float* wiN = ewih + (128+j)*FIN;
      #pragma unroll
      for (int i=0;i<FIN;i++){
        aR += x[i]*wiR[i]; aZ += x[i]*wiZ[i]; aNi += x[i]*wiN[i];
      }
      const float* whR = ewhh + j*HH;
      const float* whZ = ewhh + (64+j)*HH;
      const float* whN = ewhh + (128+j)*HH;
      #pragma unroll
      for (int k=0;k<HH;k++){
        aR += h[k]*whR[k]; aZ += h[k]*whZ[k]; aNh += h[k]*whN[k];
      }
      float rg = sigm(aR);
      float zg = sigm(aZ);
      float ng = tanhx(aNi + rg*aNh);
      float ho = hl[j*BT+tid];          // old h[j]
      hl[j*BT+tid] = (1.f-zg)*ng + zg*ho;
    }
    #pragma unroll
    for (int k=0;k<HH;k++) h[k] = hl[k*BT+tid];
  }

  // ---------------- decoder ----------------
  float lv = Xs[14*FIN];   // last0 = Xf[:, -1, 0]
  for (int t=0;t<TOUT;t++){
    #pragma unroll 1
    for (int j=0;j<HH;j++){
      float aR = dbih[j]     + dbhh[j]     + lv*dwih[j];
      float aZ = dbih[64+j]  + dbhh[64+j]  + lv*dwih[64+j];
      float aNi= dbih[128+j]               + lv*dwih[128+j];
      float aNh= dbhh[128+j];
      const float* whR = dwhh + j*HH;
      const float* whZ = dwhh + (64+j)*HH;
      const float* whN = dwhh + (128+j)*HH;
      #pragma unroll
      for (int k=0;k<HH;k++){
        aR += h[k]*whR[k]; aZ += h[k]*whZ[k]; aNh += h[k]*whN[k];
      }
      float rg = sigm(aR);
      float zg = sigm(aZ);
      float ng = tanhx(aNi + rg*aNh);
      float ho = hl[j*BT+tid];
      hl[j*BT+tid] = (1.f-zg)*ng + zg*ho;
    }
    #pragma unroll
    for (int k=0;k<HH;k++) h[k] = hl[k*BT+tid];
    float v = lb;
    #pragma unroll
    for (int k=0;k<HH;k++) v += h[k]*lw[k];
    lv = v;
    atomicAdd(&out[s*TOUT+t], wgt*v);
  }
}

extern "C" void kernel_launch(void* const* d_in, const int* in_sizes, int n_in,
                              void* d_out, int out_size, void* d_ws, size_t ws_size,
                              hipStream_t stream)
{
  // d_in: 0 A, 1 X, 2 convw2, 3 convw3, 4 convw4, 5 convb,
  //       6 enc_wih, 7 enc_whh, 8 enc_bih, 9 enc_bhh,
  //       10 dec_wih, 11 dec_whh, 12 dec_bih, 13 dec_bhh,
  //       14 lin_w, 15 lin_b, 16 embed   (all float32 per reference)
  float* out = (float*)d_out;
  hipMemsetAsync(out, 0, (size_t)out_size*sizeof(float), stream);

  dim3 g(BN_TOTAL/BT, NC);
  gru_kernel<<<g, BT, 0, stream>>>(
    (const float*)d_in[1],
    (const float*)d_in[2], (const float*)d_in[3], (const float*)d_in[4],
    (const float*)d_in[5],
    (const float*)d_in[6], (const float*)d_in[7], (const float*)d_in[8], (const float*)d_in[9],
    (const float*)d_in[10],(const float*)d_in[11],(const float*)d_in[12],(const float*)d_in[13],
    (const float*)d_in[14],(const float*)d_in[15],
    (const float*)d_in[16],
    out);
}

// Round 4
// 1796.466 us; speedup vs baseline: 3.9299x; 3.9299x over previous
//
#include <hip/hip_runtime.h>
#include <stdint.h>

typedef unsigned short u16;
typedef unsigned int   u32;
typedef float f32x4  __attribute__((ext_vector_type(4)));
typedef short bf16x8 __attribute__((ext_vector_type(8)));

#define NSEQ   800
#define TOUT   12
#define NC     9

// ---- LDS layout (bytes) ----
// B h-frags: 24 groups (ks{0,1} x nt{R0-3,Z0-7? no:R0-3,Z4-7,Nh8-11}) x 64 lanes x 16B
#define BSZ     24576
#define WSZPW   15872              // per-wave: H-scratch 8192 + CONV 7168 + XREG 512
#define HOFF    0
#define COFF    8192
#define XOFF    (8192+7168)
#define ZOFF    (BSZ + 2*WSZPW)    // 256B zero block (block-shared)
#define LDS_TOTAL (ZOFF + 256)     // 56832 B  (< 64KB, 2 blocks/CU)

__device__ __forceinline__ float bf2f(u16 u){ union{u32 i;float f;}v; v.i=((u32)u)<<16; return v.f; }
__device__ __forceinline__ u16 f2bf(float f){ union{float f;u32 i;}v; v.f=f; u32 x=v.i; return (u16)((x + 0x7fffu + ((x>>16)&1u))>>16); }
__device__ __forceinline__ float sigm(float x){ return __builtin_amdgcn_rcpf(1.f+__expf(-x)); }
__device__ __forceinline__ float tanhx(float x){ float e=__expf(2.f*x); return 1.f - 2.f*__builtin_amdgcn_rcpf(e+1.f); }

union BXU { uint4 u; bf16x8 v; };

__global__ __launch_bounds__(128, 1) void rnn_kernel(
  const float* __restrict__ X,
  const float* __restrict__ cw2, const float* __restrict__ cw3, const float* __restrict__ cw4,
  const float* __restrict__ cbv,
  const float* __restrict__ Ewih, const float* __restrict__ Ewhh,
  const float* __restrict__ Ebih, const float* __restrict__ Ebhh,
  const float* __restrict__ Dwih, const float* __restrict__ Dwhh,
  const float* __restrict__ Dbih, const float* __restrict__ Dbhh,
  const float* __restrict__ Lw,   const float* __restrict__ Lb,
  const float* __restrict__ emb,
  float* __restrict__ out)
{
  __shared__ char LDSC[LDS_TOTAL];
  const int tid = threadIdx.x;
  const int wv  = tid >> 6;        // wave in block (0/1)
  const int l   = tid & 63;        // lane
  const int q   = l >> 4;          // quad
  const int n   = l & 15;          // lane&15 -> N-col / M-row selector
  const int r   = blockIdx.y;      // channel
  const int seqbase = blockIdx.x*64 + wv*32;

  const int WB = BSZ + wv*WSZPW;
  const int HB = WB + HOFF;
  const int CB = WB + COFF;
  const int XR = WB + XOFF;

  const int Kc[NC]={2,2,2,3,3,3,4,4,4};
  const int Dc[NC]={1,2,4,1,2,4,1,2,4};
  const int K = Kc[r], D = Dc[r];
  const int L = 15 - (K-1)*D;

  // ---------- init: zero block, h-scratch zeros ----------
  if (tid < 16) *(uint4*)(LDSC + ZOFF + tid*16) = uint4{0,0,0,0};
  #pragma unroll
  for (int ks2=0; ks2<4; ks2++)
    #pragma unroll
    for (int Mt=0; Mt<2; Mt++)
      *(uint4*)(LDSC + HB + ((ks2*2+Mt)*64 + l)*16) = uint4{0,0,0,0};

  // ---------- fill B h-frag LDS (encoder whh) ----------
  // group g = ks*12 + nt; nt: 0-7 = R/Z hid-tiles (rows nt*16+..), 8-11 = Nh (rows 128+..)
  // frag element: lane fl: n_local = fl&15 (output col), k = ks*32 + (fl>>4)*8 + j
  {
    const float* whh = Ewhh + r*192*64;
    #pragma unroll 1
    for (int it=0; it<12; it++){
      int slot = it*128 + tid;
      int g = slot >> 6, fl = slot & 63;
      int ks = g/12, nt = g%12;
      int row = nt*16 + (fl&15);
      int kb  = ks*32 + (fl>>4)*8;
      u32 w[4] = {0,0,0,0};
      #pragma unroll
      for (int j=0;j<8;j++){
        float v = whh[row*64 + kb + j];
        w[j>>1] |= (u32)f2bf(v) << ((j&1)*16);
      }
      *(uint4*)(LDSC + g*1024 + fl*16) = uint4{w[0],w[1],w[2],w[3]};
    }
  }
  __syncthreads();

  // ---------- conv staging (per-wave, bf16 A-frag-ready: [t][Mt][seq16][8 feats]) ----------
  {
    const float* cw = (r<3) ? (cw2 + r*128) : (r<6) ? (cw3 + (r-3)*192) : (cw4 + (r-6)*256);
    const float* cb = cbv + r*8;
    int tot = 32*L;
    #pragma unroll 1
    for (int idx=l; idx<tot; idx+=64){
      int t = idx >> 5, sl = idx & 31;
      const float* Xp = X + (size_t)(seqbase+sl)*120 + t*8;
      float o[8];
      #pragma unroll
      for (int f=0; f<8; f++) o[f] = cb[f];
      #pragma unroll 1
      for (int kk=0; kk<K; kk++){
        const float4 x0 = *(const float4*)(Xp + kk*D*8);
        const float4 x1 = *(const float4*)(Xp + kk*D*8 + 4);
        float xv[8] = {x0.x,x0.y,x0.z,x0.w,x1.x,x1.y,x1.z,x1.w};
        #pragma unroll
        for (int f=0; f<8; f++)
          #pragma unroll
          for (int i2=0; i2<8; i2++) o[f] += xv[i2]*cw[(f*8+i2)*K + kk];
      }
      u32 w[4] = {0,0,0,0};
      #pragma unroll
      for (int f=0; f<8; f++) w[f>>1] |= (u32)f2bf(o[f]) << ((f&1)*16);
      *(uint4*)(LDSC + CB + t*512 + (sl>>4)*256 + (sl&15)*16) = uint4{w[0],w[1],w[2],w[3]};
    }
  }

  // ---------- per-lane constants ----------
  // x B-frags in registers (12: R0-3,Z4-7,Ni8-11), encoder wih
  BXU bx[12];
  {
    const float* wih = Ewih + r*192*8;
    #pragma unroll
    for (int nt=0; nt<12; nt++){
      int row = nt*16 + n;
      u32 w[4] = {0,0,0,0};
      #pragma unroll
      for (int j=0;j<8;j++){
        int kl = q*8 + j;
        float v = (kl<8) ? wih[row*8 + kl] : 0.f;
        w[j>>1] |= (u32)f2bf(v) << ((j&1)*16);
      }
      bx[nt].u = uint4{w[0],w[1],w[2],w[3]};
    }
  }
  // biases (f32), encoder
  float bR[4], bZ[4], bNi[4], bNh[4];
  {
    const float* bi = Ebih + r*192; const float* bh = Ebhh + r*192;
    #pragma unroll
    for (int ht=0; ht<4; ht++){
      int hid = ht*16 + n;
      bR[ht]  = bi[hid]     + bh[hid];
      bZ[ht]  = bi[64+hid]  + bh[64+hid];
      bNi[ht] = bi[128+hid];
      bNh[ht] =               bh[128+hid];
    }
  }
  // lin weights, lb, softmax wgt per owned seq
  float lwr[4];
  #pragma unroll
  for (int ht=0; ht<4; ht++) lwr[ht] = Lw[r*64 + ht*16 + n];
  const float lb_ = Lb[r];
  float wgt[8];
  #pragma unroll
  for (int k=0;k<8;k++){
    int s_ = seqbase + (k>>2)*16 + q*4 + (k&3);
    int nb = s_ % NSEQ;
    float e[NC], mx = -1e30f;
    #pragma unroll
    for (int c=0;c<NC;c++){ e[c] = emb[nb*NC+c]; mx = fmaxf(mx, e[c]); }
    float sm = 0.f;
    #pragma unroll
    for (int c=0;c<NC;c++) sm += __expf(e[c]-mx);
    wgt[k] = __expf(e[r]-mx) / sm;
  }

  float hO[2][4][4];
  #pragma unroll
  for (int Mt=0;Mt<2;Mt++) for (int ht=0;ht<4;ht++) for (int i=0;i<4;i++) hO[Mt][ht][i]=0.f;

  const f32x4 zf = {0.f,0.f,0.f,0.f};

  // ---------- the GRU step (MFMA + pointwise) ----------
  auto do_step = [&](int xbase){
    f32x4 acc[2][16];   // tiles: 0-3 R, 4-7 Z, 8-11 Ni, 12-15 Nh
    // x part: A x-frag (quad0 = 8 feats / lv-row; quads1-3 read zero block)
    bf16x8 ax[2];
    #pragma unroll
    for (int Mt=0; Mt<2; Mt++){
      int a_ = (q==0) ? (xbase + Mt*256 + n*16) : (ZOFF + n*16);
      ax[Mt] = *(const bf16x8*)(LDSC + a_);
    }
    #pragma unroll
    for (int nt=0; nt<12; nt++){
      #pragma unroll
      for (int Mt=0; Mt<2; Mt++)
        acc[Mt][nt] = __builtin_amdgcn_mfma_f32_16x16x32_bf16(ax[Mt], bx[nt].v, zf, 0,0,0);
    }
    // h part: hi (ks 0-1) + lo (ks 2-3), sharing B-frags
    #pragma unroll
    for (int ks=0; ks<2; ks++){
      bf16x8 ahi[2], alo[2];
      #pragma unroll
      for (int Mt=0; Mt<2; Mt++){
        ahi[Mt] = *(const bf16x8*)(LDSC + HB + (( ks   *2+Mt)*64 + l)*16);
        alo[Mt] = *(const bf16x8*)(LDSC + HB + (((ks+2)*2+Mt)*64 + l)*16);
      }
      #pragma unroll
      for (int nt=0; nt<12; nt++){
        bf16x8 b = *(const bf16x8*)(LDSC + (ks*12+nt)*1024 + l*16);
        int tile = (nt<8) ? nt : (4+nt);     // Nh tiles 12-15
        #pragma unroll
        for (int Mt=0; Mt<2; Mt++){
          f32x4 c0 = (tile>=12 && ks==0) ? zf : acc[Mt][tile];
          f32x4 t1 = __builtin_amdgcn_mfma_f32_16x16x32_bf16(ahi[Mt], b, c0, 0,0,0);
          acc[Mt][tile] = __builtin_amdgcn_mfma_f32_16x16x32_bf16(alo[Mt], b, t1, 0,0,0);
        }
      }
    }
    // pointwise + h update + write hi/lo A-frags
    #pragma unroll
    for (int Mt=0; Mt<2; Mt++){
      #pragma unroll
      for (int ht=0; ht<4; ht++){
        #pragma unroll
        for (int i=0; i<4; i++){
          float gR = acc[Mt][ht][i]    + bR[ht];
          float gZ = acc[Mt][4+ht][i]  + bZ[ht];
          float gNi= acc[Mt][8+ht][i]  + bNi[ht];
          float gNh= acc[Mt][12+ht][i] + bNh[ht];
          float rr = sigm(gR);
          float zz = sigm(gZ);
          float nn = tanhx(gNi + rr*gNh);
          float hn = (1.f-zz)*nn + zz*hO[Mt][ht][i];
          hO[Mt][ht][i] = hn;
          u16 hi = f2bf(hn);
          u16 lo = f2bf(hn - bf2f(hi));
          int ks = ht>>1;
          int fl = (q*4+i) | ((((ht&1)*2) + (n>>3)) << 4);
          int ja = (n&7)*2;
          *(u16*)(LDSC + HB + (( ks   *2+Mt)*64 + fl)*16 + ja) = hi;
          *(u16*)(LDSC + HB + (((ks+2)*2+Mt)*64 + fl)*16 + ja) = lo;
        }
      }
    }
  };

  // ---------- encoder ----------
  #pragma unroll 1
  for (int t=0; t<L; t++) do_step(CB + t*512);

  __syncthreads();
  // ---------- refill B with decoder whh ----------
  {
    const float* whh = Dwhh + r*192*64;
    #pragma unroll 1
    for (int it=0; it<12; it++){
      int slot = it*128 + tid;
      int g = slot >> 6, fl = slot & 63;
      int ks = g/12, nt = g%12;
      int row = nt*16 + (fl&15);
      int kb  = ks*32 + (fl>>4)*8;
      u32 w[4] = {0,0,0,0};
      #pragma unroll
      for (int j=0;j<8;j++){
        float v = whh[row*64 + kb + j];
        w[j>>1] |= (u32)f2bf(v) << ((j&1)*16);
      }
      *(uint4*)(LDSC + g*1024 + fl*16) = uint4{w[0],w[1],w[2],w[3]};
    }
  }
  // decoder x B-frags (dwih, K-row 0 only), decoder biases
  {
    const float* dwih = Dwih + r*192;
    #pragma unroll
    for (int nt=0; nt<12; nt++){
      int row = nt*16 + n;
      u32 w0 = (q==0) ? (u32)f2bf(dwih[row]) : 0u;   // kl==0 -> j==0,q==0
      bx[nt].u = uint4{w0,0,0,0};
    }
    const float* bi = Dbih + r*192; const float* bh = Dbhh + r*192;
    #pragma unroll
    for (int ht=0; ht<4; ht++){
      int hid = ht*16 + n;
      bR[ht]  = bi[hid]     + bh[hid];
      bZ[ht]  = bi[64+hid]  + bh[64+hid];
      bNi[ht] = bi[128+hid];
      bNh[ht] =               bh[128+hid];
    }
  }
  // init lv region: [Mt][seq16][16B] = {bf16(last0), 0...}
  if (l < 32){
    int Mt = l >> 4;
    float lv0 = X[(size_t)(seqbase+l)*120 + 14*8 + 0];
    u32 w0 = (u32)f2bf(lv0);
    *(uint4*)(LDSC + XR + Mt*256 + (l&15)*16) = uint4{w0,0,0,0};
  }
  __syncthreads();

  // ---------- decoder ----------
  #pragma unroll 1
  for (int t=0; t<TOUT; t++){
    do_step(XR);
    // v = h . lw + lb  (partial over this lane's 4 hid, butterfly over 16-lane group)
    float p[8];
    #pragma unroll
    for (int Mt=0; Mt<2; Mt++)
      #pragma unroll
      for (int i=0; i<4; i++)
        p[Mt*4+i] = hO[Mt][0][i]*lwr[0] + hO[Mt][1][i]*lwr[1]
                  + hO[Mt][2][i]*lwr[2] + hO[Mt][3][i]*lwr[3];
    #pragma unroll
    for (int m=1; m<16; m<<=1){
      #pragma unroll
      for (int k=0;k<8;k++) p[k] += __shfl_xor(p[k], m, 64);
    }
    // out atomic (lanes n<8), lv writeback (lanes 8<=n<16)
    if (n < 8){
      int k = n;
      int s_ = seqbase + (k>>2)*16 + q*4 + (k&3);
      atomicAdd(out + (size_t)s_*TOUT + t, wgt[k]*(p[k]+lb_));
    } else {
      int k = n-8;
      int Mt = k>>2, i = k&3;
      *(u16*)(LDSC + XR + Mt*256 + (q*4+i)*16) = f2bf(p[k]+lb_);
    }
  }
}

extern "C" void kernel_launch(void* const* d_in, const int* in_sizes, int n_in,
                              void* d_out, int out_size, void* d_ws, size_t ws_size,
                              hipStream_t stream)
{
  float* out = (float*)d_out;
  hipMemsetAsync(out, 0, (size_t)out_size*sizeof(float), stream);

  dim3 g(NSEQ*64/64, NC);   // 800 x 9 blocks, 64 seqs per block (2 waves x 32)
  rnn_kernel<<<g, 128, 0, stream>>>(
    (const float*)d_in[1],
    (const float*)d_in[2], (const float*)d_in[3], (const float*)d_in[4],
    (const float*)d_in[5],
    (const float*)d_in[6], (const float*)d_in[7], (const float*)d_in[8], (const float*)d_in[9],
    (const float*)d_in[10],(const float*)d_in[11],(const float*)d_in[12],(const float*)d_in[13],
    (const float*)d_in[14],(const float*)d_in[15],
    (const float*)d_in[16],
    out);
}

// Round 5
// 1652.825 us; speedup vs baseline: 4.2715x; 1.0869x over previous
//
#include <hip/hip_runtime.h>
#include <stdint.h>

typedef unsigned short u16;
typedef unsigned int   u32;
typedef float f32x4  __attribute__((ext_vector_type(4)));
typedef short bf16x8 __attribute__((ext_vector_type(8)));

#define NSEQ   800
#define TOUT   12
#define NC     9

// ---- LDS layout (bytes) ----
#define BOFF    0
#define BSZ     24576              // 24 B-frag groups x 64 lanes x 16B (coop staging)
#define OSTR    272                // o-block stride: 256B data + 16B pad (+4 banks per o)
#define RSTR    2176               // (hilo,Mt) region = 8 o-blocks (ks*4+o)
#define HSZ     (4*RSTR)           // 8704 per wave (hi/lo x Mt)
#define CSZ     7168               // conv A-frags: up to 14 t x 2 Mt x 16 seq x 16B
#define XSZ     512                // decoder lv A-frag region
#define WSZPW   (HSZ+CSZ+XSZ)      // 16384
#define ZOFF    (BSZ + 2*WSZPW)    // 57344: 256B zero block
#define LDS_TOTAL (ZOFF + 256)     // 57600

__device__ __forceinline__ float bf2f(u16 u){ union{u32 i;float f;}v; v.i=((u32)u)<<16; return v.f; }
__device__ __forceinline__ u16 f2bf(float f){ union{float f;u32 i;}v; v.f=f; u32 x=v.i; return (u16)((x + 0x7fffu + ((x>>16)&1u))>>16); }
__device__ __forceinline__ float sigm(float x){ return __builtin_amdgcn_rcpf(1.f+__expf(-x)); }
__device__ __forceinline__ float tanhx(float x){ float e=__expf(2.f*x); return 1.f - 2.f*__builtin_amdgcn_rcpf(e+1.f); }

union BXU { uint4 u; bf16x8 v; };

__global__ __launch_bounds__(128, 1) void rnn_kernel(
  const float* __restrict__ X,
  const float* __restrict__ cw2, const float* __restrict__ cw3, const float* __restrict__ cw4,
  const float* __restrict__ cbv,
  const float* __restrict__ Ewih, const float* __restrict__ Ewhh,
  const float* __restrict__ Ebih, const float* __restrict__ Ebhh,
  const float* __restrict__ Dwih, const float* __restrict__ Dwhh,
  const float* __restrict__ Dbih, const float* __restrict__ Dbhh,
  const float* __restrict__ Lw,   const float* __restrict__ Lb,
  const float* __restrict__ emb,
  float* __restrict__ out)
{
  __shared__ char LDSC[LDS_TOTAL];
  const int tid = threadIdx.x;
  const int wv  = tid >> 6;        // wave in block (0/1)
  const int l   = tid & 63;        // lane
  const int q   = l >> 4;          // quad
  const int n   = l & 15;
  const int r   = blockIdx.y;      // channel
  const int seqbase = blockIdx.x*64 + wv*32;

  const int WB = BSZ + wv*WSZPW;   // per-wave base
  const int HB = WB;               // h frag scratch
  const int CB = WB + HSZ;         // conv frags
  const int XR = WB + HSZ + CSZ;   // decoder lv frags

  const int Kc[NC]={2,2,2,3,3,3,4,4,4};
  const int Dc[NC]={1,2,4,1,2,4,1,2,4};
  const int K = Kc[r], D = Dc[r];
  const int L = 15 - (K-1)*D;

  // ---------- zero block + per-wave h-scratch zeros ----------
  if (tid < 16) *(uint4*)(LDSC + ZOFF + tid*16) = uint4{0,0,0,0};
  #pragma unroll 1
  for (int z=l; z<HSZ/16; z+=64) *(uint4*)(LDSC + HB + z*16) = uint4{0,0,0,0};

  // ---------- cooperative B staging (k-permuted whh -> bf16 B-frags) ----------
  // group g = ks*12+nt. element: lane fl holds B[k=ks*32+(fl>>4)*8+j][col=nt*16+(fl&15)]
  // k-permutation: k = 4*(hid%16) + hid/16  =>  hid = (k&3)*16 + (k>>2)
  auto stage_B = [&](const float* __restrict__ whh){
    #pragma unroll 1
    for (int it=0; it<12; it++){
      int slot = it*128 + tid;
      int g = slot >> 6, fl = slot & 63;
      int ks = g/12, nt = g%12;
      int row = nt*16 + (fl&15);
      int kb  = ks*32 + (fl>>4)*8;
      u32 w[4] = {0,0,0,0};
      #pragma unroll
      for (int j=0;j<8;j++){
        int k = kb + j;
        int hid = (k&3)*16 + (k>>2);
        float v = whh[row*64 + hid];
        w[j>>1] |= (u32)f2bf(v) << ((j&1)*16);
      }
      *(uint4*)(LDSC + BOFF + (g*64+fl)*16) = uint4{w[0],w[1],w[2],w[3]};
    }
  };

  stage_B(Ewhh + r*192*64);
  __syncthreads();

  // ---------- whh B-frags -> registers ----------
  bf16x8 bh[2][12];
  auto load_bh = [&](){
    #pragma unroll
    for (int ks=0;ks<2;ks++)
      #pragma unroll
      for (int nt=0;nt<12;nt++)
        bh[ks][nt] = *(const bf16x8*)(LDSC + BOFF + ((ks*12+nt)*64 + l)*16);
  };
  load_bh();

  // ---------- conv staging (per-wave, bf16 A-frag-ready: [t][Mt][seq16][8 feats]) ----------
  {
    const float* cw = (r<3) ? (cw2 + r*128) : (r<6) ? (cw3 + (r-3)*192) : (cw4 + (r-6)*256);
    const float* cb = cbv + r*8;
    int tot = 32*L;
    #pragma unroll 1
    for (int idx=l; idx<tot; idx+=64){
      int t = idx >> 5, sl = idx & 31;
      const float* Xp = X + (size_t)(seqbase+sl)*120 + t*8;
      float o[8];
      #pragma unroll
      for (int f=0; f<8; f++) o[f] = cb[f];
      #pragma unroll 1
      for (int kk=0; kk<K; kk++){
        const float4 x0 = *(const float4*)(Xp + kk*D*8);
        const float4 x1 = *(const float4*)(Xp + kk*D*8 + 4);
        float xv[8] = {x0.x,x0.y,x0.z,x0.w,x1.x,x1.y,x1.z,x1.w};
        #pragma unroll
        for (int f=0; f<8; f++)
          #pragma unroll
          for (int i2=0; i2<8; i2++) o[f] += xv[i2]*cw[(f*8+i2)*K + kk];
      }
      u32 w[4] = {0,0,0,0};
      #pragma unroll
      for (int f=0; f<8; f++) w[f>>1] |= (u32)f2bf(o[f]) << ((f&1)*16);
      *(uint4*)(LDSC + CB + t*512 + (sl>>4)*256 + (sl&15)*16) = uint4{w[0],w[1],w[2],w[3]};
    }
  }

  // ---------- per-lane constants ----------
  BXU bx[12];
  {
    const float* wih = Ewih + r*192*8;
    #pragma unroll
    for (int nt=0; nt<12; nt++){
      int row = nt*16 + n;
      u32 w[4] = {0,0,0,0};
      #pragma unroll
      for (int j=0;j<8;j++){
        int kl = q*8 + j;
        float v = (kl<8) ? wih[row*8 + kl] : 0.f;
        w[j>>1] |= (u32)f2bf(v) << ((j&1)*16);
      }
      bx[nt].u = uint4{w[0],w[1],w[2],w[3]};
    }
  }
  float bR[4], bZ[4], bNi[4], bNh[4];
  {
    const float* bi = Ebih + r*192; const float* bh_ = Ebhh + r*192;
    #pragma unroll
    for (int ht=0; ht<4; ht++){
      int hid = ht*16 + n;
      bR[ht]  = bi[hid]     + bh_[hid];
      bZ[ht]  = bi[64+hid]  + bh_[64+hid];
      bNi[ht] = bi[128+hid];
      bNh[ht] =               bh_[128+hid];
    }
  }
  float lwr[4];
  #pragma unroll
  for (int ht=0; ht<4; ht++) lwr[ht] = Lw[r*64 + ht*16 + n];
  const float lb_ = Lb[r];
  float wgt[8];
  #pragma unroll
  for (int k=0;k<8;k++){
    int s_ = seqbase + (k>>2)*16 + q*4 + (k&3);
    int nb = s_ % NSEQ;
    float e[NC], mx = -1e30f;
    #pragma unroll
    for (int c=0;c<NC;c++){ e[c] = emb[nb*NC+c]; mx = fmaxf(mx, e[c]); }
    float sm = 0.f;
    #pragma unroll
    for (int c=0;c<NC;c++) sm += __expf(e[c]-mx);
    wgt[k] = __expf(e[r]-mx) / sm;
  }

  float hO[2][4][4];
  #pragma unroll
  for (int Mt=0;Mt<2;Mt++) for (int ht=0;ht<4;ht++) for (int i=0;i<4;i++) hO[Mt][ht][i]=0.f;

  const f32x4 zf = {0.f,0.f,0.f,0.f};
  const int oq = l >> 4;   // reader o-octet

  // ---------- GRU step ----------
  auto do_step = [&](int xbase){
    f32x4 acc[2][16];   // tiles: 0-3 R, 4-7 Z, 8-11 Ni, 12-15 Nh
    bf16x8 ax[2];
    #pragma unroll
    for (int Mt=0; Mt<2; Mt++){
      int a_ = (q==0) ? (xbase + Mt*256 + n*16) : (ZOFF + n*16);
      ax[Mt] = *(const bf16x8*)(LDSC + a_);
    }
    #pragma unroll
    for (int nt=0; nt<12; nt++)
      #pragma unroll
      for (int Mt=0; Mt<2; Mt++)
        acc[Mt][nt] = __builtin_amdgcn_mfma_f32_16x16x32_bf16(ax[Mt], bx[nt].v, zf, 0,0,0);
    // h part: hi regions rho'=Mt, lo regions rho'=2+Mt; o-blocks (ks*4+o)*OSTR
    #pragma unroll
    for (int ks=0; ks<2; ks++){
      bf16x8 ahi[2], alo[2];
      #pragma unroll
      for (int Mt=0; Mt<2; Mt++){
        int bo = (ks*4 + oq)*OSTR + n*16;
        ahi[Mt] = *(const bf16x8*)(LDSC + HB +  Mt   *RSTR + bo);
        alo[Mt] = *(const bf16x8*)(LDSC + HB + (2+Mt)*RSTR + bo);
      }
      #pragma unroll
      for (int nt=0; nt<12; nt++){
        int tile = (nt<8) ? nt : (4+nt);
        #pragma unroll
        for (int Mt=0; Mt<2; Mt++){
          f32x4 c0 = (tile>=12 && ks==0) ? zf : acc[Mt][tile];
          f32x4 t1 = __builtin_amdgcn_mfma_f32_16x16x32_bf16(ahi[Mt], bh[ks][nt], c0, 0,0,0);
          acc[Mt][tile] = __builtin_amdgcn_mfma_f32_16x16x32_bf16(alo[Mt], bh[ks][nt], t1, 0,0,0);
        }
      }
    }
    // pointwise + h update + packed b64 writeback (k-permuted: lane's 4 ht -> consecutive k)
    const int ks_w = n>>3, o_w = (n&7)>>1;
    #pragma unroll
    for (int Mt=0; Mt<2; Mt++){
      #pragma unroll
      for (int i=0; i<4; i++){
        u32 hib[4], lob[4];
        #pragma unroll
        for (int ht=0; ht<4; ht++){
          float gR = acc[Mt][ht][i]    + bR[ht];
          float gZ = acc[Mt][4+ht][i]  + bZ[ht];
          float gNi= acc[Mt][8+ht][i]  + bNi[ht];
          float gNh= acc[Mt][12+ht][i] + bNh[ht];
          float rr = sigm(gR);
          float zz = sigm(gZ);
          float nn = tanhx(gNi + rr*gNh);
          float ho = hO[Mt][ht][i];
          float hn = nn + zz*(ho - nn);
          hO[Mt][ht][i] = hn;
          u32 hnb = __float_as_uint(hn);
          u32 hb  = hnb & 0xffff0000u;           // truncated bf16 (hi)
          float res = hn - __uint_as_float(hb);  // residual -> lo (truncated)
          hib[ht] = hb;
          lob[ht] = __float_as_uint(res);
        }
        u32 whi0 = __builtin_amdgcn_perm(hib[1], hib[0], 0x07060302u);
        u32 whi1 = __builtin_amdgcn_perm(hib[3], hib[2], 0x07060302u);
        u32 wlo0 = __builtin_amdgcn_perm(lob[1], lob[0], 0x07060302u);
        u32 wlo1 = __builtin_amdgcn_perm(lob[3], lob[2], 0x07060302u);
        int boff = (ks_w*4 + o_w)*OSTR + (q*4+i)*16 + (n&1)*8;
        uint2 vhi; vhi.x = whi0; vhi.y = whi1;
        uint2 vlo; vlo.x = wlo0; vlo.y = wlo1;
        *(uint2*)(LDSC + HB +  Mt   *RSTR + boff) = vhi;
        *(uint2*)(LDSC + HB + (2+Mt)*RSTR + boff) = vlo;
      }
    }
  };

  // ---------- encoder ----------
  #pragma unroll 1
  for (int t=0; t<L; t++) do_step(CB + t*512);

  __syncthreads();
  stage_B(Dwhh + r*192*64);
  // decoder x B-frags (dwih col, k=0 only) + decoder biases
  {
    const float* dwih = Dwih + r*192;
    #pragma unroll
    for (int nt=0; nt<12; nt++){
      int row = nt*16 + n;
      u32 w0 = (q==0) ? (u32)f2bf(dwih[row]) : 0u;
      bx[nt].u = uint4{w0,0,0,0};
    }
    const float* bi = Dbih + r*192; const float* bh_ = Dbhh + r*192;
    #pragma unroll
    for (int ht=0; ht<4; ht++){
      int hid = ht*16 + n;
      bR[ht]  = bi[hid]     + bh_[hid];
      bZ[ht]  = bi[64+hid]  + bh_[64+hid];
      bNi[ht] = bi[128+hid];
      bNh[ht] =               bh_[128+hid];
    }
  }
  // init lv region: [Mt][seq16][16B] = {bf16(last0), 0...}
  if (l < 32){
    int Mt = l >> 4;
    float lv0 = X[(size_t)(seqbase+l)*120 + 14*8 + 0];
    u32 w0 = (u32)f2bf(lv0);
    *(uint4*)(LDSC + XR + Mt*256 + (l&15)*16) = uint4{w0,0,0,0};
  }
  __syncthreads();
  load_bh();

  // ---------- decoder ----------
  #pragma unroll 1
  for (int t=0; t<TOUT; t++){
    do_step(XR);
    float p[8];
    #pragma unroll
    for (int Mt=0; Mt<2; Mt++)
      #pragma unroll
      for (int i=0; i<4; i++)
        p[Mt*4+i] = hO[Mt][0][i]*lwr[0] + hO[Mt][1][i]*lwr[1]
                  + hO[Mt][2][i]*lwr[2] + hO[Mt][3][i]*lwr[3];
    #pragma unroll
    for (int m=1; m<16; m<<=1){
      #pragma unroll
      for (int k=0;k<8;k++) p[k] += __shfl_xor(p[k], m, 64);
    }
    if (n < 8){
      int k = n;
      int s_ = seqbase + (k>>2)*16 + q*4 + (k&3);
      atomicAdd(out + (size_t)s_*TOUT + t, wgt[k]*(p[k]+lb_));
    } else {
      int k = n-8;
      int Mt = k>>2, i = k&3;
      *(u16*)(LDSC + XR + Mt*256 + (q*4+i)*16) = f2bf(p[k]+lb_);
    }
  }
}

extern "C" void kernel_launch(void* const* d_in, const int* in_sizes, int n_in,
                              void* d_out, int out_size, void* d_ws, size_t ws_size,
                              hipStream_t stream)
{
  float* out = (float*)d_out;
  hipMemsetAsync(out, 0, (size_t)out_size*sizeof(float), stream);

  dim3 g(NSEQ*64/64, NC);   // 800 x 9 blocks, 64 seqs per block (2 waves x 32)
  rnn_kernel<<<g, 128, 0, stream>>>(
    (const float*)d_in[1],
    (const float*)d_in[2], (const float*)d_in[3], (const float*)d_in[4],
    (const float*)d_in[5],
    (const float*)d_in[6], (const float*)d_in[7], (const float*)d_in[8], (const float*)d_in[9],
    (const float*)d_in[10],(const float*)d_in[11],(const float*)d_in[12],(const float*)d_in[13],
    (const float*)d_in[14],(const float*)d_in[15],
    (const float*)d_in[16],
    out);
}

// Round 6
// 1478.049 us; speedup vs baseline: 4.7766x; 1.1182x over previous
//
#include <hip/hip_runtime.h>
#include <stdint.h>

typedef unsigned short u16;
typedef unsigned int   u32;
typedef float f32x4  __attribute__((ext_vector_type(4)));
typedef short bf16x8 __attribute__((ext_vector_type(8)));

#define NSEQ 800
#define TOUT 12
#define NC   9

// ---- LDS layout (bytes) ----
#define BSZ   24576              // 24 B-frag groups x 64 lanes x 16B (block-shared whh frags)
#define RSTR  2048               // H region per (hilo*2+Mt): 8 o-blocks x 256B
#define HSZ   8192               // per wave: 4 regions (hi x Mt, lo x Mt)
#define LDS_TOTAL (BSZ + 2*HSZ)  // 40960 -> 4 blocks/CU -> 2 waves/SIMD

__device__ __forceinline__ u16 f2bf(float f){ union{float f;u32 i;}v; v.f=f; u32 x=v.i; return (u16)((x + 0x7fffu + ((x>>16)&1u))>>16); }
__device__ __forceinline__ float sigm(float x){ return __builtin_amdgcn_rcpf(1.f+__expf(-x)); }
__device__ __forceinline__ float tanhx(float x){ float e=__expf(2.f*x); return 1.f - 2.f*__builtin_amdgcn_rcpf(e+1.f); }

union BXU { uint4 u; bf16x8 v; };

__global__ __launch_bounds__(128, 2) void rnn_kernel(
  const float* __restrict__ X,
  const float* __restrict__ cw2, const float* __restrict__ cw3, const float* __restrict__ cw4,
  const float* __restrict__ cbv,
  const float* __restrict__ Ewih, const float* __restrict__ Ewhh,
  const float* __restrict__ Ebih, const float* __restrict__ Ebhh,
  const float* __restrict__ Dwih, const float* __restrict__ Dwhh,
  const float* __restrict__ Dbih, const float* __restrict__ Dbhh,
  const float* __restrict__ Lw,   const float* __restrict__ Lb,
  const float* __restrict__ emb,
  float* __restrict__ out)
{
  __shared__ char LDSC[LDS_TOTAL];
  const int tid = threadIdx.x;
  const int wv  = tid >> 6;
  const int l   = tid & 63;
  const int q   = l >> 4;
  const int n   = l & 15;
  const int r   = blockIdx.y;
  const int seqbase = blockIdx.x*64 + wv*32;
  const int HB = BSZ + wv*HSZ;

  const int Kc[NC]={2,2,2,3,3,3,4,4,4};
  const int Dc[NC]={1,2,4,1,2,4,1,2,4};
  const int K = Kc[r], D = Dc[r];
  const int L = 15 - (K-1)*D;

  // ---------- zero per-wave h-scratch ----------
  #pragma unroll
  for (int z=0; z<8; z++) *(uint4*)(LDSC + HB + (z*64+l)*16) = uint4{0,0,0,0};

  // ---------- cooperative B staging (k-permuted whh -> bf16 B-frags) ----------
  // k-permutation: k = 4*(hid%16) + hid/16
  auto stage_B = [&](const float* __restrict__ whh){
    #pragma unroll 1
    for (int it=0; it<12; it++){
      int slot = it*128 + tid;
      int g = slot >> 6, fl = slot & 63;
      int ks = g/12, nt = g%12;
      int row = nt*16 + (fl&15);
      int kb  = ks*32 + (fl>>4)*8;
      u32 w[4] = {0,0,0,0};
      #pragma unroll
      for (int j=0;j<8;j++){
        int k = kb + j;
        int hid = (k&3)*16 + (k>>2);
        w[j>>1] |= (u32)f2bf(whh[row*64 + hid]) << ((j&1)*16);
      }
      *(uint4*)(LDSC + (g*64+fl)*16) = uint4{w[0],w[1],w[2],w[3]};
    }
  };

  stage_B(Ewhh + r*192*64);

  // ---------- per-lane x B-frags: conv folded into wih  ----------
  // W~[g][k=tap*8+feat] = sum_o wih[g][o] * cw[o][feat][tap]; lane holds taps q (j=feat)
  BXU bx[12];
  {
    const float* wih = Ewih + r*192*8;
    const float* cw  = (r<3) ? (cw2 + r*128) : (r<6) ? (cw3 + (r-3)*192) : (cw4 + (r-6)*256);
    #pragma unroll 1
    for (int nt=0; nt<12; nt++){
      int row = nt*16 + n;
      float wv8[8];
      #pragma unroll
      for (int o=0;o<8;o++) wv8[o] = wih[row*8+o];
      u32 w[4] = {0,0,0,0};
      if (q < K){
        #pragma unroll
        for (int j=0;j<8;j++){
          float a = 0.f;
          #pragma unroll
          for (int o=0;o<8;o++) a += wv8[o]*cw[(o*8+j)*K + q];
          w[j>>1] |= (u32)f2bf(a) << ((j&1)*16);
        }
      }
      bx[nt].u = uint4{w[0],w[1],w[2],w[3]};
    }
  }

  // ---------- biases (f32), conv bias folded through wih ----------
  float bR[4], bZ[4], bNi[4], bNh[4];
  {
    const float* bi = Ebih + r*192; const float* bh_ = Ebhh + r*192;
    const float* wih = Ewih + r*192*8; const float* cb = cbv + r*8;
    #pragma unroll
    for (int ht=0; ht<4; ht++){
      int hid = ht*16 + n;
      float cR=0.f,cZ=0.f,cN=0.f;
      #pragma unroll
      for (int o=0;o<8;o++){
        cR += wih[hid*8+o]*cb[o];
        cZ += wih[(64+hid)*8+o]*cb[o];
        cN += wih[(128+hid)*8+o]*cb[o];
      }
      bR[ht]  = bi[hid]     + bh_[hid]     + cR;
      bZ[ht]  = bi[64+hid]  + bh_[64+hid]  + cZ;
      bNi[ht] = bi[128+hid]                + cN;
      bNh[ht] =               bh_[128+hid];
    }
  }
  float lwr[4];
  #pragma unroll
  for (int ht=0; ht<4; ht++) lwr[ht] = Lw[r*64 + ht*16 + n];
  const float lb_ = Lb[r];
  // per-lane softmax weight (only lanes n<8 use it for the atomic)
  float wgt;
  {
    int s_ = seqbase + ((n>>2)&1)*16 + q*4 + (n&3);
    int nb = s_ % NSEQ;
    float e[NC], mx = -1e30f;
    #pragma unroll
    for (int c=0;c<NC;c++){ e[c] = emb[nb*NC+c]; mx = fmaxf(mx, e[c]); }
    float sm = 0.f;
    #pragma unroll
    for (int c=0;c<NC;c++) sm += __expf(e[c]-mx);
    wgt = __expf(e[r]-mx) / sm;
  }

  float hO[2][4][4];
  #pragma unroll
  for (int Mt=0;Mt<2;Mt++) for (int ht=0;ht<4;ht++) for (int i=0;i<4;i++) hO[Mt][ht][i]=0.f;

  const f32x4 zf = {0.f,0.f,0.f,0.f};
  __syncthreads();

  // ---------- GRU step (h-MFMA first, x-MFMA last, pointwise, h writeback) ----------
  auto do_step = [&](bf16x8 ax0, bf16x8 ax1){
    f32x4 acc[2][16];   // 0-3 R, 4-7 Z, 8-11 Ni, 12-15 Nh
    #pragma unroll
    for (int ks=0; ks<2; ks++){
      bf16x8 ahi[2], alo[2];
      #pragma unroll
      for (int Mt=0; Mt<2; Mt++){
        int bo = (ks*4 + q)*256 + n*16;
        ahi[Mt] = *(const bf16x8*)(LDSC + HB +  Mt   *RSTR + bo);
        alo[Mt] = *(const bf16x8*)(LDSC + HB + (2+Mt)*RSTR + bo);
      }
      #pragma unroll
      for (int nt=0; nt<12; nt++){
        bf16x8 b = *(const bf16x8*)(LDSC + ((ks*12+nt)*64 + l)*16);
        int tile = (nt<8) ? nt : (4+nt);
        #pragma unroll
        for (int Mt=0; Mt<2; Mt++){
          f32x4 c0 = (ks==0) ? zf : acc[Mt][tile];
          f32x4 t1 = __builtin_amdgcn_mfma_f32_16x16x32_bf16(ahi[Mt], b, c0, 0,0,0);
          acc[Mt][tile] = __builtin_amdgcn_mfma_f32_16x16x32_bf16(alo[Mt], b, t1, 0,0,0);
        }
      }
    }
    #pragma unroll
    for (int nt=0; nt<12; nt++){
      #pragma unroll
      for (int Mt=0; Mt<2; Mt++){
        bf16x8 a = Mt ? ax1 : ax0;
        f32x4 c0 = (nt<8) ? acc[Mt][nt] : zf;
        acc[Mt][nt] = __builtin_amdgcn_mfma_f32_16x16x32_bf16(a, bx[nt].v, c0, 0,0,0);
      }
    }
    // pointwise + hi/lo writeback (k-permuted -> packed b64, OSTR=256)
    const int ks_w = n>>3, o_w = (n&7)>>1;
    #pragma unroll
    for (int Mt=0; Mt<2; Mt++){
      #pragma unroll
      for (int i=0; i<4; i++){
        u32 hib[4], lob[4];
        #pragma unroll
        for (int ht=0; ht<4; ht++){
          float gR = acc[Mt][ht][i]    + bR[ht];
          float gZ = acc[Mt][4+ht][i]  + bZ[ht];
          float gNi= acc[Mt][8+ht][i]  + bNi[ht];
          float gNh= acc[Mt][12+ht][i] + bNh[ht];
          float rr = sigm(gR);
          float zz = sigm(gZ);
          float nn = tanhx(gNi + rr*gNh);
          float ho = hO[Mt][ht][i];
          float hn = nn + zz*(ho - nn);
          hO[Mt][ht][i] = hn;
          u32 hnb = __float_as_uint(hn);
          u32 hb  = hnb & 0xffff0000u;
          float res = hn - __uint_as_float(hb);
          hib[ht] = hb;
          lob[ht] = __float_as_uint(res);
        }
        u32 whi0 = __builtin_amdgcn_perm(hib[1], hib[0], 0x07060302u);
        u32 whi1 = __builtin_amdgcn_perm(hib[3], hib[2], 0x07060302u);
        u32 wlo0 = __builtin_amdgcn_perm(lob[1], lob[0], 0x07060302u);
        u32 wlo1 = __builtin_amdgcn_perm(lob[3], lob[2], 0x07060302u);
        int boff = (ks_w*4 + o_w)*256 + (q*4+i)*16 + (n&1)*8;
        uint2 vhi; vhi.x = whi0; vhi.y = whi1;
        uint2 vlo; vlo.x = wlo0; vlo.y = wlo1;
        *(uint2*)(LDSC + HB +  Mt   *RSTR + boff) = vhi;
        *(uint2*)(LDSC + HB + (2+Mt)*RSTR + boff) = vlo;
      }
    }
  };

  // ---------- encoder: A = raw X window (tap q), W~ does conv+wih ----------
  const float* xb0 = X + (size_t)(seqbase +      n)*120;
  const float* xb1 = X + (size_t)(seqbase + 16 + n)*120;
  const int tapoff = ((q<K)? q : 0)*D*8;
  #pragma unroll 1
  for (int t=0; t<L; t++){
    BXU a0u, a1u;
    {
      const float* xp = xb0 + t*8 + tapoff;
      float4 v0 = *(const float4*)xp, v1 = *(const float4*)(xp+4);
      a0u.u = uint4{ (u32)f2bf(v0.x) | ((u32)f2bf(v0.y)<<16),
                     (u32)f2bf(v0.z) | ((u32)f2bf(v0.w)<<16),
                     (u32)f2bf(v1.x) | ((u32)f2bf(v1.y)<<16),
                     (u32)f2bf(v1.z) | ((u32)f2bf(v1.w)<<16) };
    }
    {
      const float* xp = xb1 + t*8 + tapoff;
      float4 v0 = *(const float4*)xp, v1 = *(const float4*)(xp+4);
      a1u.u = uint4{ (u32)f2bf(v0.x) | ((u32)f2bf(v0.y)<<16),
                     (u32)f2bf(v0.z) | ((u32)f2bf(v0.w)<<16),
                     (u32)f2bf(v1.x) | ((u32)f2bf(v1.y)<<16),
                     (u32)f2bf(v1.z) | ((u32)f2bf(v1.w)<<16) };
    }
    do_step(a0u.v, a1u.v);
  }

  // ---------- switch to decoder weights ----------
  __syncthreads();
  stage_B(Dwhh + r*192*64);
  {
    const float* dwih = Dwih + r*192;
    #pragma unroll
    for (int nt=0; nt<12; nt++){
      u32 w0 = (q==0) ? (u32)f2bf(dwih[nt*16+n]) : 0u;
      bx[nt].u = uint4{w0,0,0,0};
    }
    const float* bi = Dbih + r*192; const float* bh_ = Dbhh + r*192;
    #pragma unroll
    for (int ht=0; ht<4; ht++){
      int hid = ht*16 + n;
      bR[ht]  = bi[hid]     + bh_[hid];
      bZ[ht]  = bi[64+hid]  + bh_[64+hid];
      bNi[ht] = bi[128+hid];
      bNh[ht] =               bh_[128+hid];
    }
  }
  __syncthreads();

  // lv (decoder input) packed bf16 per Mt, init = last0
  u32 lvw[2];
  lvw[0] = (u32)f2bf(xb0[112]);
  lvw[1] = (u32)f2bf(xb1[112]);

  // ---------- decoder ----------
  #pragma unroll 1
  for (int t=0; t<TOUT; t++){
    BXU a0u, a1u;
    a0u.u = (q==0) ? uint4{lvw[0],0,0,0} : uint4{0,0,0,0};
    a1u.u = (q==0) ? uint4{lvw[1],0,0,0} : uint4{0,0,0,0};
    do_step(a0u.v, a1u.v);
    float p[8];
    #pragma unroll
    for (int Mt=0; Mt<2; Mt++)
      #pragma unroll
      for (int i=0; i<4; i++)
        p[Mt*4+i] = hO[Mt][0][i]*lwr[0] + hO[Mt][1][i]*lwr[1]
                  + hO[Mt][2][i]*lwr[2] + hO[Mt][3][i]*lwr[3];
    #pragma unroll
    for (int m=1; m<16; m<<=1){
      #pragma unroll
      for (int k=0;k<8;k++) p[k] += __shfl_xor(p[k], m, 64);
    }
    if (n < 8){
      int s_ = seqbase + (n>>2)*16 + q*4 + (n&3);
      atomicAdd(out + (size_t)s_*TOUT + t, wgt*(p[n]+lb_));
    }
    if (t+1 < TOUT){
      // lv[seq=n] = v[seq] : pick source lane whose own (n&3) matches, q_src = n>>2
      float s00 = (n&2) ? p[2] : p[0];
      float s01 = (n&2) ? p[3] : p[1];
      float se0 = ((n&1) ? s01 : s00) + lb_;
      float s10 = (n&2) ? p[6] : p[4];
      float s11 = (n&2) ? p[7] : p[5];
      float se1 = ((n&1) ? s11 : s10) + lb_;
      int src = (n>>2)*16 + (n&3);
      float lv0 = __shfl(se0, src, 64);
      float lv1 = __shfl(se1, src, 64);
      lvw[0] = (u32)f2bf(lv0);
      lvw[1] = (u32)f2bf(lv1);
    }
  }
}

extern "C" void kernel_launch(void* const* d_in, const int* in_sizes, int n_in,
                              void* d_out, int out_size, void* d_ws, size_t ws_size,
                              hipStream_t stream)
{
  float* out = (float*)d_out;
  hipMemsetAsync(out, 0, (size_t)out_size*sizeof(float), stream);

  dim3 g(NSEQ*64/64, NC);   // 800 x 9 blocks, 64 seqs per block (2 waves x 32)
  rnn_kernel<<<g, 128, 0, stream>>>(
    (const float*)d_in[1],
    (const float*)d_in[2], (const float*)d_in[3], (const float*)d_in[4],
    (const float*)d_in[5],
    (const float*)d_in[6], (const float*)d_in[7], (const float*)d_in[8], (const float*)d_in[9],
    (const float*)d_in[10],(const float*)d_in[11],(const float*)d_in[12],(const float*)d_in[13],
    (const float*)d_in[14],(const float*)d_in[15],
    (const float*)d_in[16],
    out);
}

// Round 7
// 1284.437 us; speedup vs baseline: 5.4966x; 1.1507x over previous
//
#include <hip/hip_runtime.h>
#include <hip/hip_bf16.h>
#include <stdint.h>

typedef unsigned short u16;
typedef unsigned int   u32;
typedef float f32x4  __attribute__((ext_vector_type(4)));
typedef short bf16x8 __attribute__((ext_vector_type(8)));

#define NSEQ 800
#define TOUT 12
#define NC   9

// ---- LDS layout (bytes) ----
// B-frags: 24 groups x 64 lanes x 16B = 24576 (block-shared)
// H-scratch per wave: 4 regions (hi/lo x Mt) x 2048, swizzled cell layout:
//   cell(ks,o,row) @ (row&3)*512 + o*128 + ks*64 + (row>>2)*16   (16B per cell)
#define BSZ   24576
#define RSTR  2048
#define HSZ   8192
#define LDS_TOTAL (BSZ + 2*HSZ)  // 40960 -> 4 blocks/CU -> 2 waves/SIMD

__device__ __forceinline__ u16 f2bf(float f){ union{float f;u32 i;}v; v.f=f; u32 x=v.i; return (u16)((x + 0x7fffu + ((x>>16)&1u))>>16); }
__device__ __forceinline__ u32 pkbf(float a, float b){
  union{ __hip_bfloat162 h2; u32 u; } v;
  v.h2 = __float22bfloat162_rn(float2{a,b});
  return v.u;
}
__device__ __forceinline__ float sigm(float x){ return __builtin_amdgcn_rcpf(1.f+__expf(-x)); }
__device__ __forceinline__ float tanhx(float x){ float e=__expf(2.f*x); return 1.f - 2.f*__builtin_amdgcn_rcpf(e+1.f); }

union BXU { uint4 u; bf16x8 v; };

__global__ __launch_bounds__(128, 2) void rnn_kernel(
  const float* __restrict__ X,
  const float* __restrict__ cw2, const float* __restrict__ cw3, const float* __restrict__ cw4,
  const float* __restrict__ cbv,
  const float* __restrict__ Ewih, const float* __restrict__ Ewhh,
  const float* __restrict__ Ebih, const float* __restrict__ Ebhh,
  const float* __restrict__ Dwih, const float* __restrict__ Dwhh,
  const float* __restrict__ Dbih, const float* __restrict__ Dbhh,
  const float* __restrict__ Lw,   const float* __restrict__ Lb,
  const float* __restrict__ emb,
  float* __restrict__ out)
{
  __shared__ char LDSC[LDS_TOTAL];
  const int tid = threadIdx.x;
  const int wv  = tid >> 6;
  const int l   = tid & 63;
  const int q   = l >> 4;
  const int n   = l & 15;
  const int r   = blockIdx.y;
  const int seqbase = blockIdx.x*64 + wv*32;
  const int HB = BSZ + wv*HSZ;

  const int Kc[NC]={2,2,2,3,3,3,4,4,4};
  const int Dc[NC]={1,2,4,1,2,4,1,2,4};
  const int K = Kc[r], D = Dc[r];
  const int L = 15 - (K-1)*D;

  // ---------- zero per-wave h-scratch ----------
  #pragma unroll
  for (int z=0; z<8; z++) *(uint4*)(LDSC + HB + (z*64+l)*16) = uint4{0,0,0,0};

  // ---------- cooperative B staging (k-permuted whh -> bf16 B-frags) ----------
  // k-permutation: k = 4*(hid%16) + hid/16
  auto stage_B = [&](const float* __restrict__ whh){
    #pragma unroll 1
    for (int it=0; it<12; it++){
      int slot = it*128 + tid;
      int g = slot >> 6, fl = slot & 63;
      int ks = g/12, nt = g%12;
      int row = nt*16 + (fl&15);
      int kb  = ks*32 + (fl>>4)*8;
      u32 w[4] = {0,0,0,0};
      #pragma unroll
      for (int j=0;j<8;j++){
        int k = kb + j;
        int hid = (k&3)*16 + (k>>2);
        w[j>>1] |= (u32)f2bf(whh[row*64 + hid]) << ((j&1)*16);
      }
      *(uint4*)(LDSC + (g*64+fl)*16) = uint4{w[0],w[1],w[2],w[3]};
    }
  };

  stage_B(Ewhh + r*192*64);

  // ---------- per-lane x B-frags: conv folded into wih ----------
  BXU bx[12];
  {
    const float* wih = Ewih + r*192*8;
    const float* cw  = (r<3) ? (cw2 + r*128) : (r<6) ? (cw3 + (r-3)*192) : (cw4 + (r-6)*256);
    #pragma unroll 1
    for (int nt=0; nt<12; nt++){
      int row = nt*16 + n;
      float wv8[8];
      #pragma unroll
      for (int o=0;o<8;o++) wv8[o] = wih[row*8+o];
      u32 w[4] = {0,0,0,0};
      if (q < K){
        #pragma unroll
        for (int j=0;j<8;j++){
          float a = 0.f;
          #pragma unroll
          for (int o=0;o<8;o++) a += wv8[o]*cw[(o*8+j)*K + q];
          w[j>>1] |= (u32)f2bf(a) << ((j&1)*16);
        }
      }
      bx[nt].u = uint4{w[0],w[1],w[2],w[3]};
    }
  }

  // ---------- biases (f32), conv bias folded through wih ----------
  float bR4[4], bZ4[4], bNi4[4], bNh4[4];
  {
    const float* bi = Ebih + r*192; const float* bh_ = Ebhh + r*192;
    const float* wih = Ewih + r*192*8; const float* cb = cbv + r*8;
    #pragma unroll
    for (int ht=0; ht<4; ht++){
      int hid = ht*16 + n;
      float cR=0.f,cZ=0.f,cN=0.f;
      #pragma unroll
      for (int o=0;o<8;o++){
        cR += wih[hid*8+o]*cb[o];
        cZ += wih[(64+hid)*8+o]*cb[o];
        cN += wih[(128+hid)*8+o]*cb[o];
      }
      bR4[ht]  = bi[hid]     + bh_[hid]     + cR;
      bZ4[ht]  = bi[64+hid]  + bh_[64+hid]  + cZ;
      bNi4[ht] = bi[128+hid]                + cN;
      bNh4[ht] =               bh_[128+hid];
    }
  }
  float lwr[4];
  #pragma unroll
  for (int ht=0; ht<4; ht++) lwr[ht] = Lw[r*64 + ht*16 + n];
  const float lb_ = Lb[r];
  float wgt;
  {
    int s_ = seqbase + ((n>>2)&1)*16 + q*4 + (n&3);
    int nb = s_ % NSEQ;
    float e[NC], mx = -1e30f;
    #pragma unroll
    for (int c=0;c<NC;c++){ e[c] = emb[nb*NC+c]; mx = fmaxf(mx, e[c]); }
    float sm = 0.f;
    #pragma unroll
    for (int c=0;c<NC;c++) sm += __expf(e[c]-mx);
    wgt = __expf(e[r]-mx) / sm;
  }

  float hO[2][4][4];
  #pragma unroll
  for (int Mt=0;Mt<2;Mt++) for (int ht=0;ht<4;ht++) for (int i=0;i<4;i++) hO[Mt][ht][i]=0.f;

  const f32x4 zf = {0.f,0.f,0.f,0.f};
  __syncthreads();

  // ---------- GRU step: ht-pair blocked (acc live = 64 regs) ----------
  const int ks_w = n>>3, o_w = (n&7)>>1;
  auto do_step = [&](bf16x8 ax0, bf16x8 ax1){
    // A h-frags: 8 b128 reads (swizzled layout, 2-way banks = free)
    bf16x8 ahl[2][2][2];   // [hilo][ks][Mt]
    #pragma unroll
    for (int ks=0; ks<2; ks++){
      int bo = (n&3)*512 + q*128 + ks*64 + (n>>2)*16;
      #pragma unroll
      for (int Mt=0; Mt<2; Mt++){
        ahl[0][ks][Mt] = *(const bf16x8*)(LDSC + HB +  Mt   *RSTR + bo);
        ahl[1][ks][Mt] = *(const bf16x8*)(LDSC + HB + (2+Mt)*RSTR + bo);
      }
    }
    #pragma unroll
    for (int hp=0; hp<2; hp++){
      f32x4 acc[2][2][4];   // [u][Mt][R,Z,Ni,Nh]
      #pragma unroll
      for (int u=0; u<2; u++){
        int ht = hp*2+u;
        #pragma unroll
        for (int Mt=0; Mt<2; Mt++){
          bf16x8 a = Mt ? ax1 : ax0;
          acc[u][Mt][0] = __builtin_amdgcn_mfma_f32_16x16x32_bf16(a, bx[ht].v,   zf, 0,0,0);
          acc[u][Mt][1] = __builtin_amdgcn_mfma_f32_16x16x32_bf16(a, bx[4+ht].v, zf, 0,0,0);
          acc[u][Mt][2] = __builtin_amdgcn_mfma_f32_16x16x32_bf16(a, bx[8+ht].v, zf, 0,0,0);
          acc[u][Mt][3] = zf;
        }
        #pragma unroll
        for (int ks=0; ks<2; ks++){
          bf16x8 fbR = *(const bf16x8*)(LDSC + ((ks*12 +   ht)*64 + l)*16);
          bf16x8 fbZ = *(const bf16x8*)(LDSC + ((ks*12 + 4+ht)*64 + l)*16);
          bf16x8 fbN = *(const bf16x8*)(LDSC + ((ks*12 + 8+ht)*64 + l)*16);
          #pragma unroll
          for (int Mt=0; Mt<2; Mt++){
            acc[u][Mt][0] = __builtin_amdgcn_mfma_f32_16x16x32_bf16(ahl[0][ks][Mt], fbR, acc[u][Mt][0], 0,0,0);
            acc[u][Mt][0] = __builtin_amdgcn_mfma_f32_16x16x32_bf16(ahl[1][ks][Mt], fbR, acc[u][Mt][0], 0,0,0);
            acc[u][Mt][1] = __builtin_amdgcn_mfma_f32_16x16x32_bf16(ahl[0][ks][Mt], fbZ, acc[u][Mt][1], 0,0,0);
            acc[u][Mt][1] = __builtin_amdgcn_mfma_f32_16x16x32_bf16(ahl[1][ks][Mt], fbZ, acc[u][Mt][1], 0,0,0);
            acc[u][Mt][3] = __builtin_amdgcn_mfma_f32_16x16x32_bf16(ahl[0][ks][Mt], fbN, acc[u][Mt][3], 0,0,0);
            acc[u][Mt][3] = __builtin_amdgcn_mfma_f32_16x16x32_bf16(ahl[1][ks][Mt], fbN, acc[u][Mt][3], 0,0,0);
          }
        }
      }
      // pointwise for the pair; b32 writes, full-bank coverage
      #pragma unroll
      for (int Mt=0; Mt<2; Mt++){
        #pragma unroll
        for (int i=0; i<4; i++){
          float hn2[2], res2[2];
          #pragma unroll
          for (int u=0; u<2; u++){
            int ht = hp*2+u;
            float gR = acc[u][Mt][0][i] + bR4[ht];
            float gZ = acc[u][Mt][1][i] + bZ4[ht];
            float gNi= acc[u][Mt][2][i] + bNi4[ht];
            float gNh= acc[u][Mt][3][i] + bNh4[ht];
            float rr = sigm(gR);
            float zz = sigm(gZ);
            float nn = tanhx(gNi + rr*gNh);
            float ho = hO[Mt][ht][i];
            float hn = nn + zz*(ho - nn);
            hO[Mt][ht][i] = hn;
            u32 hb = __float_as_uint(hn) & 0xffff0000u;
            hn2[u]  = __uint_as_float(hb);
            res2[u] = hn - hn2[u];
          }
          u32 whi = pkbf(hn2[0],  hn2[1]);    // truncated-hi halves pack exactly
          u32 wlo = pkbf(res2[0], res2[1]);
          int boff = i*512 + o_w*128 + ks_w*64 + q*16 + (n&1)*8 + hp*4;
          *(u32*)(LDSC + HB +  Mt   *RSTR + boff) = whi;
          *(u32*)(LDSC + HB + (2+Mt)*RSTR + boff) = wlo;
        }
      }
    }
  };

  // ---------- encoder: A = raw X window (tap q), W~ does conv+wih ----------
  const float* xb0 = X + (size_t)(seqbase +      n)*120;
  const float* xb1 = X + (size_t)(seqbase + 16 + n)*120;
  const int tapoff = ((q<K)? q : 0)*D*8;
  float4 c00 = *(const float4*)(xb0 + tapoff);
  float4 c01 = *(const float4*)(xb0 + tapoff + 4);
  float4 c10 = *(const float4*)(xb1 + tapoff);
  float4 c11 = *(const float4*)(xb1 + tapoff + 4);
  #pragma unroll 1
  for (int t=0; t<L; t++){
    float4 n00, n01, n10, n11;
    if (t+1 < L){
      n00 = *(const float4*)(xb0 + (t+1)*8 + tapoff);
      n01 = *(const float4*)(xb0 + (t+1)*8 + tapoff + 4);
      n10 = *(const float4*)(xb1 + (t+1)*8 + tapoff);
      n11 = *(const float4*)(xb1 + (t+1)*8 + tapoff + 4);
    }
    BXU a0u, a1u;
    a0u.u = uint4{ pkbf(c00.x,c00.y), pkbf(c00.z,c00.w), pkbf(c01.x,c01.y), pkbf(c01.z,c01.w) };
    a1u.u = uint4{ pkbf(c10.x,c10.y), pkbf(c10.z,c10.w), pkbf(c11.x,c11.y), pkbf(c11.z,c11.w) };
    do_step(a0u.v, a1u.v);
    c00=n00; c01=n01; c10=n10; c11=n11;
  }

  // ---------- switch to decoder weights ----------
  __syncthreads();
  stage_B(Dwhh + r*192*64);
  {
    const float* dwih = Dwih + r*192;
    #pragma unroll
    for (int nt=0; nt<12; nt++){
      u32 w0 = (q==0) ? (u32)f2bf(dwih[nt*16+n]) : 0u;
      bx[nt].u = uint4{w0,0,0,0};
    }
    const float* bi = Dbih + r*192; const float* bh_ = Dbhh + r*192;
    #pragma unroll
    for (int ht=0; ht<4; ht++){
      int hid = ht*16 + n;
      bR4[ht]  = bi[hid]     + bh_[hid];
      bZ4[ht]  = bi[64+hid]  + bh_[64+hid];
      bNi4[ht] = bi[128+hid];
      bNh4[ht] =               bh_[128+hid];
    }
  }
  __syncthreads();

  // lv (decoder input) packed bf16 per Mt, init = last0
  u32 lvw[2];
  lvw[0] = (u32)f2bf(xb0[112]);
  lvw[1] = (u32)f2bf(xb1[112]);

  // ---------- decoder ----------
  #pragma unroll 1
  for (int t=0; t<TOUT; t++){
    BXU a0u, a1u;
    a0u.u = (q==0) ? uint4{lvw[0],0,0,0} : uint4{0,0,0,0};
    a1u.u = (q==0) ? uint4{lvw[1],0,0,0} : uint4{0,0,0,0};
    do_step(a0u.v, a1u.v);
    float p[8];
    #pragma unroll
    for (int Mt=0; Mt<2; Mt++)
      #pragma unroll
      for (int i=0; i<4; i++)
        p[Mt*4+i] = hO[Mt][0][i]*lwr[0] + hO[Mt][1][i]*lwr[1]
                  + hO[Mt][2][i]*lwr[2] + hO[Mt][3][i]*lwr[3];
    #pragma unroll
    for (int m=1; m<16; m<<=1){
      #pragma unroll
      for (int k=0;k<8;k++) p[k] += __shfl_xor(p[k], m, 64);
    }
    if (n < 8){
      int s_ = seqbase + (n>>2)*16 + q*4 + (n&3);
      atomicAdd(out + (size_t)s_*TOUT + t, wgt*(p[n]+lb_));
    }
    if (t+1 < TOUT){
      float s00 = (n&2) ? p[2] : p[0];
      float s01 = (n&2) ? p[3] : p[1];
      float se0 = ((n&1) ? s01 : s00) + lb_;
      float s10 = (n&2) ? p[6] : p[4];
      float s11 = (n&2) ? p[7] : p[5];
      float se1 = ((n&1) ? s11 : s10) + lb_;
      int src = (n>>2)*16 + (n&3);
      float lv0 = __shfl(se0, src, 64);
      float lv1 = __shfl(se1, src, 64);
      lvw[0] = (u32)f2bf(lv0);
      lvw[1] = (u32)f2bf(lv1);
    }
  }
}

extern "C" void kernel_launch(void* const* d_in, const int* in_sizes, int n_in,
                              void* d_out, int out_size, void* d_ws, size_t ws_size,
                              hipStream_t stream)
{
  float* out = (float*)d_out;
  hipMemsetAsync(out, 0, (size_t)out_size*sizeof(float), stream);

  dim3 g(NSEQ*64/64, NC);   // 800 x 9 blocks, 64 seqs per block (2 waves x 32)
  rnn_kernel<<<g, 128, 0, stream>>>(
    (const float*)d_in[1],
    (const float*)d_in[2], (const float*)d_in[3], (const float*)d_in[4],
    (const float*)d_in[5],
    (const float*)d_in[6], (const float*)d_in[7], (const float*)d_in[8], (const float*)d_in[9],
    (const float*)d_in[10],(const float*)d_in[11],(const float*)d_in[12],(const float*)d_in[13],
    (const float*)d_in[14],(const float*)d_in[15],
    (const float*)d_in[16],
    out);
}

// Round 8
// 1257.381 us; speedup vs baseline: 5.6148x; 1.0215x over previous
//
#include <hip/hip_runtime.h>
#include <hip/hip_bf16.h>
#include <stdint.h>

typedef unsigned short u16;
typedef unsigned int   u32;
typedef float f32x4  __attribute__((ext_vector_type(4)));
typedef short bf16x8 __attribute__((ext_vector_type(8)));

#define NSEQ 800
#define TOUT 12
#define NC   9

// ---- LDS layout (bytes) ----
// B-frags: 24 groups x 64 lanes x 16B = 24576 (block-shared)
// H-scratch per wave: 4 regions (hi,Mt0)(hi,Mt1)(lo,Mt0)(lo,Mt1) x 2048
// cell(row,o,ks) @ C*16, C = [(row&3)*4 + (row>>3)*2 + ks]*8 + o*2 + ((row>>2)&1)
//   -> reads (row=n, o=q) conflict-free; writes 4-way (min for b32 here)
#define BSZ   24576
#define RSTR  2048
#define HSZ   8192
#define LDS_TOTAL (BSZ + 2*HSZ)  // 40960 -> 4 blocks/CU -> 2 waves/SIMD

__device__ __forceinline__ u16 f2bf(float f){ union{float f;u32 i;}v; v.f=f; u32 x=v.i; return (u16)((x + 0x7fffu + ((x>>16)&1u))>>16); }
__device__ __forceinline__ u32 pkbf(float a, float b){
  union{ __hip_bfloat162 h2; u32 u; } v;
  v.h2 = __float22bfloat162_rn(float2{a,b});
  return v.u;
}
__device__ __forceinline__ float sigm(float x){ return __builtin_amdgcn_rcpf(1.f+__expf(-x)); }
__device__ __forceinline__ float tanhx(float x){ float e=__expf(2.f*x); return 1.f - 2.f*__builtin_amdgcn_rcpf(e+1.f); }

union BXU { uint4 u; bf16x8 v; };

__global__ __launch_bounds__(128, 2) void rnn_kernel(
  const float* __restrict__ X,
  const float* __restrict__ cw2, const float* __restrict__ cw3, const float* __restrict__ cw4,
  const float* __restrict__ cbv,
  const float* __restrict__ Ewih, const float* __restrict__ Ewhh,
  const float* __restrict__ Ebih, const float* __restrict__ Ebhh,
  const float* __restrict__ Dwih, const float* __restrict__ Dwhh,
  const float* __restrict__ Dbih, const float* __restrict__ Dbhh,
  const float* __restrict__ Lw,   const float* __restrict__ Lb,
  const float* __restrict__ emb,
  float* __restrict__ out)
{
  __shared__ char LDSC[LDS_TOTAL];
  const int tid = threadIdx.x;
  const int wv  = tid >> 6;
  const int l   = tid & 63;
  const int q   = l >> 4;
  const int n   = l & 15;
  const int r   = blockIdx.y;
  const int seqbase = blockIdx.x*64 + wv*32;
  const int HB = BSZ + wv*HSZ;

  const int Kc[NC]={2,2,2,3,3,3,4,4,4};
  const int Dc[NC]={1,2,4,1,2,4,1,2,4};
  const int K = Kc[r], D = Dc[r];
  const int L = 15 - (K-1)*D;

  // ---------- zero per-wave h-scratch ----------
  #pragma unroll
  for (int z=0; z<8; z++) *(uint4*)(LDSC + HB + (z*64+l)*16) = uint4{0,0,0,0};

  // ---------- cooperative B staging (k-permuted whh -> bf16 B-frags) ----------
  // k-permutation: k = 4*(hid%16) + hid/16
  auto stage_B = [&](const float* __restrict__ whh){
    #pragma unroll 1
    for (int it=0; it<12; it++){
      int slot = it*128 + tid;
      int g = slot >> 6, fl = slot & 63;
      int ks = g/12, nt = g%12;
      int row = nt*16 + (fl&15);
      int kb  = ks*32 + (fl>>4)*8;
      u32 w[4] = {0,0,0,0};
      #pragma unroll
      for (int j=0;j<8;j++){
        int k = kb + j;
        int hid = (k&3)*16 + (k>>2);
        w[j>>1] |= (u32)f2bf(whh[row*64 + hid]) << ((j&1)*16);
      }
      *(uint4*)(LDSC + (g*64+fl)*16) = uint4{w[0],w[1],w[2],w[3]};
    }
  };

  stage_B(Ewhh + r*192*64);

  // ---------- per-lane x B-frags: conv folded into wih ----------
  BXU bx[12];
  {
    const float* wih = Ewih + r*192*8;
    const float* cw  = (r<3) ? (cw2 + r*128) : (r<6) ? (cw3 + (r-3)*192) : (cw4 + (r-6)*256);
    #pragma unroll 1
    for (int nt=0; nt<12; nt++){
      int row = nt*16 + n;
      float wv8[8];
      #pragma unroll
      for (int o=0;o<8;o++) wv8[o] = wih[row*8+o];
      u32 w[4] = {0,0,0,0};
      if (q < K){
        #pragma unroll
        for (int j=0;j<8;j++){
          float a = 0.f;
          #pragma unroll
          for (int o=0;o<8;o++) a += wv8[o]*cw[(o*8+j)*K + q];
          w[j>>1] |= (u32)f2bf(a) << ((j&1)*16);
        }
      }
      bx[nt].u = uint4{w[0],w[1],w[2],w[3]};
    }
  }

  // ---------- biases (f32), conv bias folded through wih ----------
  float bR4[4], bZ4[4], bNi4[4], bNh4[4];
  {
    const float* bi = Ebih + r*192; const float* bh_ = Ebhh + r*192;
    const float* wih = Ewih + r*192*8; const float* cb = cbv + r*8;
    #pragma unroll
    for (int ht=0; ht<4; ht++){
      int hid = ht*16 + n;
      float cR=0.f,cZ=0.f,cN=0.f;
      #pragma unroll
      for (int o=0;o<8;o++){
        cR += wih[hid*8+o]*cb[o];
        cZ += wih[(64+hid)*8+o]*cb[o];
        cN += wih[(128+hid)*8+o]*cb[o];
      }
      bR4[ht]  = bi[hid]     + bh_[hid]     + cR;
      bZ4[ht]  = bi[64+hid]  + bh_[64+hid]  + cZ;
      bNi4[ht] = bi[128+hid]                + cN;
      bNh4[ht] =               bh_[128+hid];
    }
  }
  float lwr[4];
  #pragma unroll
  for (int ht=0; ht<4; ht++) lwr[ht] = Lw[r*64 + ht*16 + n];
  const float lb_ = Lb[r];
  float wgt;
  {
    int s_ = seqbase + ((n>>2)&1)*16 + q*4 + (n&3);
    int nb = s_ % NSEQ;
    float e[NC], mx = -1e30f;
    #pragma unroll
    for (int c=0;c<NC;c++){ e[c] = emb[nb*NC+c]; mx = fmaxf(mx, e[c]); }
    float sm = 0.f;
    #pragma unroll
    for (int c=0;c<NC;c++) sm += __expf(e[c]-mx);
    wgt = __expf(e[r]-mx) / sm;
  }

  float hO[2][4][4];
  #pragma unroll
  for (int Mt=0;Mt<2;Mt++) for (int ht=0;ht<4;ht++) for (int i=0;i<4;i++) hO[Mt][ht][i]=0.f;

  const f32x4 zf = {0.f,0.f,0.f,0.f};
  __syncthreads();

  // ---------- GRU step: ht-pair blocked (acc live = 64 regs) ----------
  // H write base (per lane): swizzled layout, see top comment
  const int wbase = ((q>>1)*256) + ((n>>3)*128) + (((n>>1)&3)*32) + ((q&1)*16) + ((n&1)*8);
  const int rbase = (n&3)*512 + (n>>3)*256 + ((n>>2)&1)*16 + q*32;
  auto do_step = [&](bf16x8 ax0, bf16x8 ax1){
    bf16x8 ahl[2][2][2];   // [hilo][ks][Mt]
    #pragma unroll
    for (int ks=0; ks<2; ks++){
      int bo = rbase + ks*128;
      #pragma unroll
      for (int Mt=0; Mt<2; Mt++){
        ahl[0][ks][Mt] = *(const bf16x8*)(LDSC + HB +  Mt   *RSTR + bo);
        ahl[1][ks][Mt] = *(const bf16x8*)(LDSC + HB + (2+Mt)*RSTR + bo);
      }
    }
    #pragma unroll
    for (int hp=0; hp<2; hp++){
      f32x4 acc[2][2][4];   // [u][Mt][R,Z,Ni,Nh]
      #pragma unroll
      for (int u=0; u<2; u++){
        int ht = hp*2+u;
        #pragma unroll
        for (int Mt=0; Mt<2; Mt++){
          bf16x8 a = Mt ? ax1 : ax0;
          acc[u][Mt][0] = __builtin_amdgcn_mfma_f32_16x16x32_bf16(a, bx[ht].v,   zf, 0,0,0);
          acc[u][Mt][1] = __builtin_amdgcn_mfma_f32_16x16x32_bf16(a, bx[4+ht].v, zf, 0,0,0);
          acc[u][Mt][2] = __builtin_amdgcn_mfma_f32_16x16x32_bf16(a, bx[8+ht].v, zf, 0,0,0);
          acc[u][Mt][3] = zf;
        }
        #pragma unroll
        for (int ks=0; ks<2; ks++){
          bf16x8 fbR = *(const bf16x8*)(LDSC + ((ks*12 +   ht)*64 + l)*16);
          bf16x8 fbZ = *(const bf16x8*)(LDSC + ((ks*12 + 4+ht)*64 + l)*16);
          bf16x8 fbN = *(const bf16x8*)(LDSC + ((ks*12 + 8+ht)*64 + l)*16);
          #pragma unroll
          for (int Mt=0; Mt<2; Mt++){
            acc[u][Mt][0] = __builtin_amdgcn_mfma_f32_16x16x32_bf16(ahl[0][ks][Mt], fbR, acc[u][Mt][0], 0,0,0);
            acc[u][Mt][0] = __builtin_amdgcn_mfma_f32_16x16x32_bf16(ahl[1][ks][Mt], fbR, acc[u][Mt][0], 0,0,0);
            acc[u][Mt][1] = __builtin_amdgcn_mfma_f32_16x16x32_bf16(ahl[0][ks][Mt], fbZ, acc[u][Mt][1], 0,0,0);
            acc[u][Mt][1] = __builtin_amdgcn_mfma_f32_16x16x32_bf16(ahl[1][ks][Mt], fbZ, acc[u][Mt][1], 0,0,0);
            acc[u][Mt][3] = __builtin_amdgcn_mfma_f32_16x16x32_bf16(ahl[0][ks][Mt], fbN, acc[u][Mt][3], 0,0,0);
            acc[u][Mt][3] = __builtin_amdgcn_mfma_f32_16x16x32_bf16(ahl[1][ks][Mt], fbN, acc[u][Mt][3], 0,0,0);
          }
        }
      }
      // pointwise for the pair; packed b32 writes
      #pragma unroll
      for (int Mt=0; Mt<2; Mt++){
        #pragma unroll
        for (int i=0; i<4; i++){
          float hn2[2], res2[2];
          #pragma unroll
          for (int u=0; u<2; u++){
            int ht = hp*2+u;
            float gR = acc[u][Mt][0][i] + bR4[ht];
            float gZ = acc[u][Mt][1][i] + bZ4[ht];
            float gNi= acc[u][Mt][2][i] + bNi4[ht];
            float gNh= acc[u][Mt][3][i] + bNh4[ht];
            float rr = sigm(gR);
            float zz = sigm(gZ);
            float nn = tanhx(gNi + rr*gNh);
            float ho = hO[Mt][ht][i];
            float hn = nn + zz*(ho - nn);
            hO[Mt][ht][i] = hn;
            u32 hb = __float_as_uint(hn) & 0xffff0000u;
            hn2[u]  = __uint_as_float(hb);
            res2[u] = hn - hn2[u];
          }
          u32 whi = pkbf(hn2[0],  hn2[1]);    // truncated-hi halves pack exactly
          u32 wlo = pkbf(res2[0], res2[1]);
          int boff = i*512 + wbase + hp*4;
          *(u32*)(LDSC + HB +  Mt   *RSTR + boff) = whi;
          *(u32*)(LDSC + HB + (2+Mt)*RSTR + boff) = wlo;
        }
      }
    }
  };

  // ---------- encoder: A = raw X window (tap q), W~ does conv+wih ----------
  const float* xb0 = X + (size_t)(seqbase +      n)*120;
  const float* xb1 = X + (size_t)(seqbase + 16 + n)*120;
  const int tapoff = ((q<K)? q : 0)*D*8;
  float4 c00 = *(const float4*)(xb0 + tapoff);
  float4 c01 = *(const float4*)(xb0 + tapoff + 4);
  float4 c10 = *(const float4*)(xb1 + tapoff);
  float4 c11 = *(const float4*)(xb1 + tapoff + 4);
  #pragma unroll 1
  for (int t=0; t<L; t++){
    BXU a0u, a1u;
    a0u.u = uint4{ pkbf(c00.x,c00.y), pkbf(c00.z,c00.w), pkbf(c01.x,c01.y), pkbf(c01.z,c01.w) };
    a1u.u = uint4{ pkbf(c10.x,c10.y), pkbf(c10.z,c10.w), pkbf(c11.x,c11.y), pkbf(c11.z,c11.w) };
    if (t+1 < L){
      c00 = *(const float4*)(xb0 + (t+1)*8 + tapoff);
      c01 = *(const float4*)(xb0 + (t+1)*8 + tapoff + 4);
      c10 = *(const float4*)(xb1 + (t+1)*8 + tapoff);
      c11 = *(const float4*)(xb1 + (t+1)*8 + tapoff + 4);
    }
    do_step(a0u.v, a1u.v);
  }

  // ---------- switch to decoder weights ----------
  __syncthreads();
  stage_B(Dwhh + r*192*64);
  {
    const float* dwih = Dwih + r*192;
    #pragma unroll
    for (int nt=0; nt<12; nt++){
      u32 w0 = (q==0) ? (u32)f2bf(dwih[nt*16+n]) : 0u;
      bx[nt].u = uint4{w0,0,0,0};
    }
    const float* bi = Dbih + r*192; const float* bh_ = Dbhh + r*192;
    #pragma unroll
    for (int ht=0; ht<4; ht++){
      int hid = ht*16 + n;
      bR4[ht]  = bi[hid]     + bh_[hid];
      bZ4[ht]  = bi[64+hid]  + bh_[64+hid];
      bNi4[ht] = bi[128+hid];
      bNh4[ht] =               bh_[128+hid];
    }
  }
  __syncthreads();

  // lv (decoder input) packed bf16 per Mt, init = last0
  u32 lvw[2];
  lvw[0] = (u32)f2bf(xb0[112]);
  lvw[1] = (u32)f2bf(xb1[112]);

  // ---------- decoder ----------
  #pragma unroll 1
  for (int t=0; t<TOUT; t++){
    BXU a0u, a1u;
    a0u.u = (q==0) ? uint4{lvw[0],0,0,0} : uint4{0,0,0,0};
    a1u.u = (q==0) ? uint4{lvw[1],0,0,0} : uint4{0,0,0,0};
    do_step(a0u.v, a1u.v);
    float p[8];
    #pragma unroll
    for (int Mt=0; Mt<2; Mt++)
      #pragma unroll
      for (int i=0; i<4; i++)
        p[Mt*4+i] = hO[Mt][0][i]*lwr[0] + hO[Mt][1][i]*lwr[1]
                  + hO[Mt][2][i]*lwr[2] + hO[Mt][3][i]*lwr[3];
    #pragma unroll
    for (int m=1; m<16; m<<=1){
      #pragma unroll
      for (int k=0;k<8;k++) p[k] += __shfl_xor(p[k], m, 64);
    }
    if (n < 8){
      int s_ = seqbase + (n>>2)*16 + q*4 + (n&3);
      atomicAdd(out + (size_t)s_*TOUT + t, wgt*(p[n]+lb_));
    }
    if (t+1 < TOUT){
      float s00 = (n&2) ? p[2] : p[0];
      float s01 = (n&2) ? p[3] : p[1];
      float se0 = ((n&1) ? s01 : s00) + lb_;
      float s10 = (n&2) ? p[6] : p[4];
      float s11 = (n&2) ? p[7] : p[5];
      float se1 = ((n&1) ? s11 : s10) + lb_;
      int src = (n>>2)*16 + (n&3);
      float lv0 = __shfl(se0, src, 64);
      float lv1 = __shfl(se1, src, 64);
      lvw[0] = (u32)f2bf(lv0);
      lvw[1] = (u32)f2bf(lv1);
    }
  }
}

extern "C" void kernel_launch(void* const* d_in, const int* in_sizes, int n_in,
                              void* d_out, int out_size, void* d_ws, size_t ws_size,
                              hipStream_t stream)
{
  float* out = (float*)d_out;
  hipMemsetAsync(out, 0, (size_t)out_size*sizeof(float), stream);

  dim3 g(NSEQ*64/64, NC);   // 800 x 9 blocks, 64 seqs per block (2 waves x 32)
  rnn_kernel<<<g, 128, 0, stream>>>(
    (const float*)d_in[1],
    (const float*)d_in[2], (const float*)d_in[3], (const float*)d_in[4],
    (const float*)d_in[5],
    (const float*)d_in[6], (const float*)d_in[7], (const float*)d_in[8], (const float*)d_in[9],
    (const float*)d_in[10],(const float*)d_in[11],(const float*)d_in[12],(const float*)d_in[13],
    (const float*)d_in[14],(const float*)d_in[15],
    (const float*)d_in[16],
    out);
}